// Round 14
// baseline (173.053 us; speedup 1.0000x reference)
//
#include <hip/hip_runtime.h>

typedef _Float16 half8  __attribute__((ext_vector_type(8)));
typedef _Float16 half4v __attribute__((ext_vector_type(4)));
typedef _Float16 half2v __attribute__((ext_vector_type(2)));
typedef float    floatx4 __attribute__((ext_vector_type(4)));
typedef float    float2v __attribute__((ext_vector_type(2)));

static constexpr float INV2PI = 0.15915494309189535f;  // rev scaling (cos path)
static constexpr float INVPI  = 0.3183098861837907f;   // half-period scaling (poly path)
static constexpr float RLOG   = 3.82843f;

// Fused activation (cos path): x0 = 0.5+0.5cos(2*pi*a); two logistic iters.
// With u = cos^2:  h = A + u*(B + D*u).
static constexpr double RD = (double)RLOG;
static constexpr float ACT_A = (float)(RD*RD/4.0 - RD*RD*RD/16.0);
static constexpr float ACT_B = (float)(-RD*RD/4.0 + RD*RD*RD/8.0);
static constexpr float ACT_D = (float)(-RD*RD*RD/16.0);

// Poly path (no transcendental): with z scaled so g = cos(2*pi*z) has the
// u-period, r = fract(z), s = r-1/2, sigma = s^2, P(sigma) ~= cos(2*pi*s)
// (deg-7 Taylor, err <= 1e-5), g = -P, and h = alpha + beta*g + gamma*g^2
//  -> h = alpha - beta*P + gamma*P^2.  (alpha=A+B/2+D/4, beta=(B+D)/2, gamma=D/4)
static constexpr float P_ALP = 0.9553469f;
static constexpr float P_NB  = 0.0785838f;   // -beta
static constexpr float P_GAM = -0.8767631f;
static constexpr float PC0 = 1.0f;
static constexpr float PC1 = -19.7392088f;   // -(2pi^2)
static constexpr float PC2 = 64.9393940f;
static constexpr float PC3 = -85.4568f;
static constexpr float PC4 = 60.2464f;
static constexpr float PC5 = -26.4266f;
static constexpr float PC6 = 7.90448f;
static constexpr float PC7 = -1.71457f;

__device__ __forceinline__ float act_rev(float a) {
    float c = __builtin_amdgcn_cosf(a);
    float u = c * c;
    float t = __builtin_fmaf(ACT_D, u, ACT_B);
    return __builtin_fmaf(u, t, ACT_A);
}

// cos-path: two C-frags (tiles t, t+2) -> next-layer B-frag. 8 v_cos (trans
// pipe) + 3 pk ops per 2 elems.
__device__ __forceinline__ half8 act8(floatx4 a, floatx4 b) {
    float2v c0 = { __builtin_amdgcn_cosf(a[0]), __builtin_amdgcn_cosf(a[1]) };
    float2v c1 = { __builtin_amdgcn_cosf(a[2]), __builtin_amdgcn_cosf(a[3]) };
    float2v c2 = { __builtin_amdgcn_cosf(b[0]), __builtin_amdgcn_cosf(b[1]) };
    float2v c3 = { __builtin_amdgcn_cosf(b[2]), __builtin_amdgcn_cosf(b[3]) };
    float2v u0 = c0*c0, u1 = c1*c1, u2 = c2*c2, u3 = c3*c3;
    float2v t0 = __builtin_elementwise_fma(u0, (float2v)(ACT_D), (float2v)(ACT_B));
    float2v t1 = __builtin_elementwise_fma(u1, (float2v)(ACT_D), (float2v)(ACT_B));
    float2v t2 = __builtin_elementwise_fma(u2, (float2v)(ACT_D), (float2v)(ACT_B));
    float2v t3 = __builtin_elementwise_fma(u3, (float2v)(ACT_D), (float2v)(ACT_B));
    float2v h0 = __builtin_elementwise_fma(u0, t0, (float2v)(ACT_A));
    float2v h1 = __builtin_elementwise_fma(u1, t1, (float2v)(ACT_A));
    float2v h2 = __builtin_elementwise_fma(u2, t2, (float2v)(ACT_A));
    float2v h3 = __builtin_elementwise_fma(u3, t3, (float2v)(ACT_A));
    half2v e0 = __builtin_bit_cast(half2v, __builtin_amdgcn_cvt_pkrtz(h0.x, h0.y));
    half2v e1 = __builtin_bit_cast(half2v, __builtin_amdgcn_cvt_pkrtz(h1.x, h1.y));
    half2v e2 = __builtin_bit_cast(half2v, __builtin_amdgcn_cvt_pkrtz(h2.x, h2.y));
    half2v e3 = __builtin_bit_cast(half2v, __builtin_amdgcn_cvt_pkrtz(h3.x, h3.y));
    half4v lo = __builtin_shufflevector(e0, e1, 0, 1, 2, 3);
    half4v hi = __builtin_shufflevector(e2, e3, 0, 1, 2, 3);
    return __builtin_shufflevector(lo, hi, 0, 1, 2, 3, 4, 5, 6, 7);
}

__device__ __forceinline__ float2v act2poly(float2v z) {
    float2v r = { __builtin_amdgcn_fractf(z.x), __builtin_amdgcn_fractf(z.y) };
    float2v s = r - (float2v)(0.5f);
    float2v g = s * s;                         // sigma
    float2v p = __builtin_elementwise_fma((float2v)(PC7), g, (float2v)(PC6));
    p = __builtin_elementwise_fma(p, g, (float2v)(PC5));
    p = __builtin_elementwise_fma(p, g, (float2v)(PC4));
    p = __builtin_elementwise_fma(p, g, (float2v)(PC3));
    p = __builtin_elementwise_fma(p, g, (float2v)(PC2));
    p = __builtin_elementwise_fma(p, g, (float2v)(PC1));
    p = __builtin_elementwise_fma(p, g, (float2v)(PC0));
    float2v t = __builtin_elementwise_fma((float2v)(P_GAM), p, (float2v)(P_NB));
    return __builtin_elementwise_fma(t, p, (float2v)(P_ALP));
}

// poly-path act8: no transcendental -- runs on the VALU pipe, relieving the
// saturated trans pipe (v_cos is quarter-rate: 8 cyc/wave; 50/tile = ~85%
// trans-pipe busy was the R10-R13 plateau wall).
__device__ __forceinline__ half8 act8poly(floatx4 a, floatx4 b) {
    float2v h0 = act2poly(float2v{a[0], a[1]});
    float2v h1 = act2poly(float2v{a[2], a[3]});
    float2v h2 = act2poly(float2v{b[0], b[1]});
    float2v h3 = act2poly(float2v{b[2], b[3]});
    half2v e0 = __builtin_bit_cast(half2v, __builtin_amdgcn_cvt_pkrtz(h0.x, h0.y));
    half2v e1 = __builtin_bit_cast(half2v, __builtin_amdgcn_cvt_pkrtz(h1.x, h1.y));
    half2v e2 = __builtin_bit_cast(half2v, __builtin_amdgcn_cvt_pkrtz(h2.x, h2.y));
    half2v e3 = __builtin_bit_cast(half2v, __builtin_amdgcn_cvt_pkrtz(h3.x, h3.y));
    half4v lo = __builtin_shufflevector(e0, e1, 0, 1, 2, 3);
    half4v hi = __builtin_shufflevector(e2, e3, 0, 1, 2, 3);
    return __builtin_shufflevector(lo, hi, 0, 1, 2, 3, 4, 5, 6, 7);
}

// Per-block LDS weight cache (R11-proven; R12 showed biases in regs spill at
// the (512,8) 64-reg cap). W2 rows for tiles 0,2 (and their biases) are
// scaled by 1/pi instead of 1/2pi: those outputs go through the poly path.
struct SMem {
    half8   w2[8][64];   // [(t*2+c)][lane]
    half8   w3[8][64];
    floatx4 b2[4][64];   // [t][lane]
    floatx4 b3[4][64];
};

__global__ __launch_bounds__(512, 8) void mlp_fused(
    const float* __restrict__ x,
    const float* __restrict__ W1, const float* __restrict__ b1,
    const float* __restrict__ W2, const float* __restrict__ b2,
    const float* __restrict__ W3, const float* __restrict__ b3,
    const float* __restrict__ W4, const float* __restrict__ b4,
    float* __restrict__ out, int N)
{
    __shared__ SMem sm;
    const int lane = threadIdx.x & 63;
    const int wib  = threadIdx.x >> 6;   // 0..7
    const int m    = lane & 15;   // sample / C col / A row
    const int q    = lane >> 4;   // quad
    const float s  = INV2PI;
    const floatx4 zero4 = {0.0f, 0.0f, 0.0f, 0.0f};

    // ---- in-register persistent frags (small): L1 and L4 ----
    half8 w1f[4];
    #pragma unroll
    for (int t = 0; t < 4; ++t) {
        half8 v = {};
        if (q == 0) {
            const int n = 16 * t + m;
            float w0 = W1[2*n] * s, w1 = W1[2*n+1] * s, bb = b1[n] * s;
            _Float16 w0h = (_Float16)w0; float w0l = w0 - (float)w0h;
            _Float16 w1h = (_Float16)w1; float w1l = w1 - (float)w1h;
            _Float16 bh  = (_Float16)bb; float bl  = bb - (float)bh;
            v[0] = w0h; v[1] = w0h; v[2] = (_Float16)w0l;
            v[3] = w1h; v[4] = w1h; v[5] = (_Float16)w1l;
            v[6] = bh;  v[7] = (_Float16)bl;
        }
        w1f[t] = v;
    }
    // L4 A-frag: only out-row m==0 real; sigma column permutation
    //   sigma: k-slot (c,q,j) -> neuron (j<4 ? 16c+4q+j : 16(c+2)+4q+j-4)
    half8 w4f[2] = {half8{}, half8{}};
    if (m == 0) {
        #pragma unroll
        for (int c = 0; c < 2; ++c)
            #pragma unroll
            for (int j = 0; j < 8; ++j) {
                int nu = (j < 4) ? (16 * c + 4 * q + j) : (16 * (c + 2) + 4 * q + j - 4);
                w4f[c][j] = (_Float16)(W4[nu] * s);
            }
    }
    floatx4 a4init = zero4;
    if (q == 0) a4init[0] = b4[0] * s;       // C row 0 = (q=0, r=0)

    // ---- wave-split LDS prep (sigma-permuted columns), one barrier ----
    if (wib == 0) {
        #pragma unroll
        for (int t = 0; t < 4; ++t) {
            const float sc2 = (t == 0 || t == 2) ? INVPI : INV2PI;  // poly tiles
            const float* r2 = W2 + (16 * t + m) * 64;
            #pragma unroll
            for (int c = 0; c < 2; ++c) {
                floatx4 lo2 = *(const floatx4*)(r2 + 16 * c + 4 * q);
                floatx4 hi2 = *(const floatx4*)(r2 + 16 * (c + 2) + 4 * q);
                half8 v2;
                #pragma unroll
                for (int j = 0; j < 4; ++j) {
                    v2[j]     = (_Float16)(lo2[j] * sc2);
                    v2[4 + j] = (_Float16)(hi2[j] * sc2);
                }
                sm.w2[t * 2 + c][lane] = v2;
            }
        }
    } else if (wib == 1) {
        #pragma unroll
        for (int t = 0; t < 4; ++t) {
            const float* r3 = W3 + (16 * t + m) * 64;
            #pragma unroll
            for (int c = 0; c < 2; ++c) {
                floatx4 lo3 = *(const floatx4*)(r3 + 16 * c + 4 * q);
                floatx4 hi3 = *(const floatx4*)(r3 + 16 * (c + 2) + 4 * q);
                half8 v3;
                #pragma unroll
                for (int j = 0; j < 4; ++j) {
                    v3[j]     = (_Float16)(lo3[j] * s);
                    v3[4 + j] = (_Float16)(hi3[j] * s);
                }
                sm.w3[t * 2 + c][lane] = v3;
            }
        }
    } else if (wib == 2) {
        #pragma unroll
        for (int t = 0; t < 4; ++t) {
            const float sc2 = (t == 0 || t == 2) ? INVPI : INV2PI;
            sm.b2[t][lane] = *(const floatx4*)(b2 + 16 * t + 4 * q) * sc2;
            sm.b3[t][lane] = *(const floatx4*)(b3 + 16 * t + 4 * q) * s;
        }
    }
    __syncthreads();

    const int ntiles = N >> 4;
    const int nwaves = (gridDim.x * blockDim.x) >> 6;
    const int gwave  = (int)(blockIdx.x * blockDim.x + threadIdx.x) >> 6;
    const float2* __restrict__ x2 = (const float2*)x;

    int tile = gwave;
    float2 xv = x2[(tile << 4) + m];          // 1-ahead x prefetch
    while (tile < ntiles) {
        const int nt = tile + nwaves;
        float2 xnext;
        if (nt < ntiles) xnext = x2[(nt << 4) + m];

        // L1 B-frag (lanes q==0): [xh, xl, xh, yh, yl, yh, 1, 1]
        half8 xa = {};
        if (q == 0) {
            _Float16 xh = (_Float16)xv.x; float xl = xv.x - (float)xh;
            _Float16 yh = (_Float16)xv.y; float yl = xv.y - (float)yh;
            xa[0] = xh; xa[1] = (_Float16)xl; xa[2] = xh;
            xa[3] = yh; xa[4] = (_Float16)yl; xa[5] = yh;
            xa[6] = (_Float16)1.0f; xa[7] = (_Float16)1.0f;
        }

        // ---- layer 1 (in-register frags) ----
        floatx4 a0 = __builtin_amdgcn_mfma_f32_16x16x32_f16(w1f[0], xa, zero4, 0, 0, 0);
        floatx4 a1 = __builtin_amdgcn_mfma_f32_16x16x32_f16(w1f[1], xa, zero4, 0, 0, 0);
        floatx4 a2 = __builtin_amdgcn_mfma_f32_16x16x32_f16(w1f[2], xa, zero4, 0, 0, 0);
        floatx4 a3 = __builtin_amdgcn_mfma_f32_16x16x32_f16(w1f[3], xa, zero4, 0, 0, 0);
        half8 B0 = act8(a0, a2);
        half8 B1 = act8(a1, a3);

        // Opaque zero per layer: defeats LICM (else LDS reads hoist into
        // ~128 live regs and spill) and staggers reads per layer.
        int z2 = 0; asm volatile("" : "+v"(z2));
        const int l2i = lane + z2;
        a0 = __builtin_amdgcn_mfma_f32_16x16x32_f16(sm.w2[0][l2i], B0, sm.b2[0][l2i], 0, 0, 0);
        a1 = __builtin_amdgcn_mfma_f32_16x16x32_f16(sm.w2[2][l2i], B0, sm.b2[1][l2i], 0, 0, 0);
        a2 = __builtin_amdgcn_mfma_f32_16x16x32_f16(sm.w2[4][l2i], B0, sm.b2[2][l2i], 0, 0, 0);
        a3 = __builtin_amdgcn_mfma_f32_16x16x32_f16(sm.w2[6][l2i], B0, sm.b2[3][l2i], 0, 0, 0);
        a0 = __builtin_amdgcn_mfma_f32_16x16x32_f16(sm.w2[1][l2i], B1, a0, 0, 0, 0);
        a1 = __builtin_amdgcn_mfma_f32_16x16x32_f16(sm.w2[3][l2i], B1, a1, 0, 0, 0);
        a2 = __builtin_amdgcn_mfma_f32_16x16x32_f16(sm.w2[5][l2i], B1, a2, 0, 0, 0);
        a3 = __builtin_amdgcn_mfma_f32_16x16x32_f16(sm.w2[7][l2i], B1, a3, 0, 0, 0);
        half8 C0 = act8poly(a0, a2);   // tiles 0,2: poly path (weights pre-scaled 1/pi)
        half8 C1 = act8(a1, a3);       // tiles 1,3: cos path

        int z3 = 0; asm volatile("" : "+v"(z3));
        const int l3i = lane + z3;
        a0 = __builtin_amdgcn_mfma_f32_16x16x32_f16(sm.w3[0][l3i], C0, sm.b3[0][l3i], 0, 0, 0);
        a1 = __builtin_amdgcn_mfma_f32_16x16x32_f16(sm.w3[2][l3i], C0, sm.b3[1][l3i], 0, 0, 0);
        a2 = __builtin_amdgcn_mfma_f32_16x16x32_f16(sm.w3[4][l3i], C0, sm.b3[2][l3i], 0, 0, 0);
        a3 = __builtin_amdgcn_mfma_f32_16x16x32_f16(sm.w3[6][l3i], C0, sm.b3[3][l3i], 0, 0, 0);
        a0 = __builtin_amdgcn_mfma_f32_16x16x32_f16(sm.w3[1][l3i], C1, a0, 0, 0, 0);
        a1 = __builtin_amdgcn_mfma_f32_16x16x32_f16(sm.w3[3][l3i], C1, a1, 0, 0, 0);
        a2 = __builtin_amdgcn_mfma_f32_16x16x32_f16(sm.w3[5][l3i], C1, a2, 0, 0, 0);
        a3 = __builtin_amdgcn_mfma_f32_16x16x32_f16(sm.w3[7][l3i], C1, a3, 0, 0, 0);
        half8 D0 = act8(a0, a2);
        half8 D1 = act8(a1, a3);

        // ---- layer 4 + store ----
        floatx4 a4 = __builtin_amdgcn_mfma_f32_16x16x32_f16(w4f[0], D0, a4init, 0, 0, 0);
        a4 = __builtin_amdgcn_mfma_f32_16x16x32_f16(w4f[1], D1, a4, 0, 0, 0);
        if (q == 0)
            out[(tile << 4) + m] = act_rev(a4[0]);

        xv = xnext;
        tile = nt;
    }
}

extern "C" void kernel_launch(void* const* d_in, const int* in_sizes, int n_in,
                              void* d_out, int out_size, void* d_ws, size_t ws_size,
                              hipStream_t stream) {
    const float* x  = (const float*)d_in[0];
    const float* W1 = (const float*)d_in[1];
    const float* b1 = (const float*)d_in[2];
    const float* W2 = (const float*)d_in[3];
    const float* b2 = (const float*)d_in[4];
    const float* W3 = (const float*)d_in[5];
    const float* b3 = (const float*)d_in[6];
    const float* W4 = (const float*)d_in[7];
    const float* b4 = (const float*)d_in[8];
    float* out = (float*)d_out;
    const int N = out_size;          // 2097152, divisible by 16

    // 2048 blocks x 8 waves = 16384 waves (R11's best-measured config);
    // 131072 tiles -> 8 tiles/wave.
    mlp_fused<<<dim3(2048), dim3(512), 0, stream>>>(x, W1, b1, W2, b2, W3, b3, W4, b4, out, N);
}

// Round 15
// 168.719 us; speedup vs baseline: 1.0257x; 1.0257x over previous
//
#include <hip/hip_runtime.h>

typedef _Float16 half8  __attribute__((ext_vector_type(8)));
typedef _Float16 half4v __attribute__((ext_vector_type(4)));
typedef _Float16 half2v __attribute__((ext_vector_type(2)));
typedef float    floatx4 __attribute__((ext_vector_type(4)));
typedef float    float2v __attribute__((ext_vector_type(2)));

static constexpr float INV2PI = 0.15915494309189535f;  // fold rad->rev into weights
static constexpr float RLOG   = 3.82843f;

// Fused activation: x0 = 0.5+0.5cos(2*pi*a); two logistic iters.
// With u = cos^2:  h = A + u*(B + D*u).  (All-cos: R8 and R14 both proved
// polynomial replacements issue MORE VALU slots than cos+3FMA.)
static constexpr double RD = (double)RLOG;
static constexpr float ACT_A = (float)(RD*RD/4.0 - RD*RD*RD/16.0);
static constexpr float ACT_B = (float)(-RD*RD/4.0 + RD*RD*RD/8.0);
static constexpr float ACT_D = (float)(-RD*RD*RD/16.0);

__device__ __forceinline__ float act_rev(float a) {
    float c = __builtin_amdgcn_cosf(a);
    float u = c * c;
    float t = __builtin_fmaf(ACT_D, u, ACT_B);
    return __builtin_fmaf(u, t, ACT_A);
}

// Two C-frags (tiles t, t+2) -> next-layer B-frag directly (no cat shuffles).
__device__ __forceinline__ half8 act8(floatx4 a, floatx4 b) {
    float2v c0 = { __builtin_amdgcn_cosf(a[0]), __builtin_amdgcn_cosf(a[1]) };
    float2v c1 = { __builtin_amdgcn_cosf(a[2]), __builtin_amdgcn_cosf(a[3]) };
    float2v c2 = { __builtin_amdgcn_cosf(b[0]), __builtin_amdgcn_cosf(b[1]) };
    float2v c3 = { __builtin_amdgcn_cosf(b[2]), __builtin_amdgcn_cosf(b[3]) };
    float2v u0 = c0*c0, u1 = c1*c1, u2 = c2*c2, u3 = c3*c3;
    float2v t0 = __builtin_elementwise_fma(u0, (float2v)(ACT_D), (float2v)(ACT_B));
    float2v t1 = __builtin_elementwise_fma(u1, (float2v)(ACT_D), (float2v)(ACT_B));
    float2v t2 = __builtin_elementwise_fma(u2, (float2v)(ACT_D), (float2v)(ACT_B));
    float2v t3 = __builtin_elementwise_fma(u3, (float2v)(ACT_D), (float2v)(ACT_B));
    float2v h0 = __builtin_elementwise_fma(u0, t0, (float2v)(ACT_A));
    float2v h1 = __builtin_elementwise_fma(u1, t1, (float2v)(ACT_A));
    float2v h2 = __builtin_elementwise_fma(u2, t2, (float2v)(ACT_A));
    float2v h3 = __builtin_elementwise_fma(u3, t3, (float2v)(ACT_A));
    half2v e0 = __builtin_bit_cast(half2v, __builtin_amdgcn_cvt_pkrtz(h0.x, h0.y));
    half2v e1 = __builtin_bit_cast(half2v, __builtin_amdgcn_cvt_pkrtz(h1.x, h1.y));
    half2v e2 = __builtin_bit_cast(half2v, __builtin_amdgcn_cvt_pkrtz(h2.x, h2.y));
    half2v e3 = __builtin_bit_cast(half2v, __builtin_amdgcn_cvt_pkrtz(h3.x, h3.y));
    half4v lo = __builtin_shufflevector(e0, e1, 0, 1, 2, 3);
    half4v hi = __builtin_shufflevector(e2, e3, 0, 1, 2, 3);
    return __builtin_shufflevector(lo, hi, 0, 1, 2, 3, 4, 5, 6, 7);
}

// Per-block LDS weight cache (R9/R11-proven). 2-tile jam: both tiles share
// every LDS weight operand (CSE halves reads) and provide 8 independent
// mfma->act chains per wave to fill latency stalls (R10-R13: no pipe
// saturated, occupancy-insensitive ~99us plateau => latency-bound).
// launch_bounds(256,5): 5 blocks/CU (123KB LDS), 20 waves/CU, 102-reg cap
// for the doubled transient state. Biases stay in LDS (R12: regs spill).
struct SMem {
    half8   w2[8][64];   // [(t*2+c)][lane]
    half8   w3[8][64];
    floatx4 b2[4][64];   // [t][lane]
    floatx4 b3[4][64];
};

__global__ __launch_bounds__(256, 5) void mlp_fused(
    const float* __restrict__ x,
    const float* __restrict__ W1, const float* __restrict__ b1,
    const float* __restrict__ W2, const float* __restrict__ b2,
    const float* __restrict__ W3, const float* __restrict__ b3,
    const float* __restrict__ W4, const float* __restrict__ b4,
    float* __restrict__ out, int N)
{
    __shared__ SMem sm;
    const int lane = threadIdx.x & 63;
    const int wib  = threadIdx.x >> 6;   // 0..3
    const int m    = lane & 15;   // sample / C col / A row
    const int q    = lane >> 4;   // quad
    const float s  = INV2PI;
    const floatx4 zero4 = {0.0f, 0.0f, 0.0f, 0.0f};

    // ---- in-register persistent frags (small): L1 and L4 ----
    // L1 A-frag (tile t), lanes q==0: [w0h, w0h, w0l, w1h, w1h, w1l, b1h, b1l]
    half8 w1f[4];
    #pragma unroll
    for (int t = 0; t < 4; ++t) {
        half8 v = {};
        if (q == 0) {
            const int n = 16 * t + m;
            float w0 = W1[2*n] * s, w1 = W1[2*n+1] * s, bb = b1[n] * s;
            _Float16 w0h = (_Float16)w0; float w0l = w0 - (float)w0h;
            _Float16 w1h = (_Float16)w1; float w1l = w1 - (float)w1h;
            _Float16 bh  = (_Float16)bb; float bl  = bb - (float)bh;
            v[0] = w0h; v[1] = w0h; v[2] = (_Float16)w0l;
            v[3] = w1h; v[4] = w1h; v[5] = (_Float16)w1l;
            v[6] = bh;  v[7] = (_Float16)bl;
        }
        w1f[t] = v;
    }
    // L4 A-frag: only out-row m==0 real; sigma column permutation
    //   sigma: k-slot (c,q,j) -> neuron (j<4 ? 16c+4q+j : 16(c+2)+4q+j-4)
    half8 w4f[2] = {half8{}, half8{}};
    if (m == 0) {
        #pragma unroll
        for (int c = 0; c < 2; ++c)
            #pragma unroll
            for (int j = 0; j < 8; ++j) {
                int nu = (j < 4) ? (16 * c + 4 * q + j) : (16 * (c + 2) + 4 * q + j - 4);
                w4f[c][j] = (_Float16)(W4[nu] * s);
            }
    }
    floatx4 a4init = zero4;
    if (q == 0) a4init[0] = b4[0] * s;       // C row 0 = (q=0, r=0)

    // ---- wave-split LDS prep (sigma-permuted columns), one barrier ----
    if (wib == 0) {
        #pragma unroll
        for (int t = 0; t < 4; ++t) {
            const float* r2 = W2 + (16 * t + m) * 64;
            #pragma unroll
            for (int c = 0; c < 2; ++c) {
                floatx4 lo2 = *(const floatx4*)(r2 + 16 * c + 4 * q);
                floatx4 hi2 = *(const floatx4*)(r2 + 16 * (c + 2) + 4 * q);
                half8 v2;
                #pragma unroll
                for (int j = 0; j < 4; ++j) {
                    v2[j]     = (_Float16)(lo2[j] * s);
                    v2[4 + j] = (_Float16)(hi2[j] * s);
                }
                sm.w2[t * 2 + c][lane] = v2;
            }
        }
    } else if (wib == 1) {
        #pragma unroll
        for (int t = 0; t < 4; ++t) {
            const float* r3 = W3 + (16 * t + m) * 64;
            #pragma unroll
            for (int c = 0; c < 2; ++c) {
                floatx4 lo3 = *(const floatx4*)(r3 + 16 * c + 4 * q);
                floatx4 hi3 = *(const floatx4*)(r3 + 16 * (c + 2) + 4 * q);
                half8 v3;
                #pragma unroll
                for (int j = 0; j < 4; ++j) {
                    v3[j]     = (_Float16)(lo3[j] * s);
                    v3[4 + j] = (_Float16)(hi3[j] * s);
                }
                sm.w3[t * 2 + c][lane] = v3;
            }
        }
    } else if (wib == 2) {
        #pragma unroll
        for (int t = 0; t < 4; ++t) {
            sm.b2[t][lane] = *(const floatx4*)(b2 + 16 * t + 4 * q) * s;
            sm.b3[t][lane] = *(const floatx4*)(b3 + 16 * t + 4 * q) * s;
        }
    }
    __syncthreads();

    const int npairs = N >> 5;               // pairs of 16-row tiles
    const int nwaves = (gridDim.x * blockDim.x) >> 6;
    const int gwave  = (int)(blockIdx.x * blockDim.x + threadIdx.x) >> 6;
    const float2* __restrict__ x2 = (const float2*)x;

    int pair = gwave;
    float2 xv0 = x2[(pair << 5) + m];
    float2 xv1 = x2[(pair << 5) + 16 + m];
    while (pair < npairs) {
        const int np = pair + nwaves;
        float2 xn0, xn1;
        if (np < npairs) {
            xn0 = x2[(np << 5) + m];
            xn1 = x2[(np << 5) + 16 + m];
        }

        // L1 B-frags (lanes q==0): [xh, xl, xh, yh, yl, yh, 1, 1]
        half8 xa[2] = {half8{}, half8{}};
        if (q == 0) {
            float2 xs[2] = {xv0, xv1};
            #pragma unroll
            for (int u = 0; u < 2; ++u) {
                _Float16 xh = (_Float16)xs[u].x; float xl = xs[u].x - (float)xh;
                _Float16 yh = (_Float16)xs[u].y; float yl = xs[u].y - (float)yh;
                xa[u][0] = xh; xa[u][1] = (_Float16)xl; xa[u][2] = xh;
                xa[u][3] = yh; xa[u][4] = (_Float16)yl; xa[u][5] = yh;
                xa[u][6] = (_Float16)1.0f; xa[u][7] = (_Float16)1.0f;
            }
        }

        // ---- layer 1 (two independent chains) ----
        half8 B0[2], B1[2];
        #pragma unroll
        for (int u = 0; u < 2; ++u) {
            floatx4 a0 = __builtin_amdgcn_mfma_f32_16x16x32_f16(w1f[0], xa[u], zero4, 0, 0, 0);
            floatx4 a1 = __builtin_amdgcn_mfma_f32_16x16x32_f16(w1f[1], xa[u], zero4, 0, 0, 0);
            floatx4 a2 = __builtin_amdgcn_mfma_f32_16x16x32_f16(w1f[2], xa[u], zero4, 0, 0, 0);
            floatx4 a3 = __builtin_amdgcn_mfma_f32_16x16x32_f16(w1f[3], xa[u], zero4, 0, 0, 0);
            B0[u] = act8(a0, a2);
            B1[u] = act8(a1, a3);
        }

        // Opaque zero per layer: defeats LICM (hoisted LDS reads would
        // become ~96 live regs and spill); reads are shared by both u-chains.
        int z2 = 0; asm volatile("" : "+v"(z2));
        const int l2i = lane + z2;
        half8 C0[2], C1[2];
        #pragma unroll
        for (int u = 0; u < 2; ++u) {
            floatx4 a0 = __builtin_amdgcn_mfma_f32_16x16x32_f16(sm.w2[0][l2i], B0[u], sm.b2[0][l2i], 0, 0, 0);
            floatx4 a1 = __builtin_amdgcn_mfma_f32_16x16x32_f16(sm.w2[2][l2i], B0[u], sm.b2[1][l2i], 0, 0, 0);
            floatx4 a2 = __builtin_amdgcn_mfma_f32_16x16x32_f16(sm.w2[4][l2i], B0[u], sm.b2[2][l2i], 0, 0, 0);
            floatx4 a3 = __builtin_amdgcn_mfma_f32_16x16x32_f16(sm.w2[6][l2i], B0[u], sm.b2[3][l2i], 0, 0, 0);
            a0 = __builtin_amdgcn_mfma_f32_16x16x32_f16(sm.w2[1][l2i], B1[u], a0, 0, 0, 0);
            a1 = __builtin_amdgcn_mfma_f32_16x16x32_f16(sm.w2[3][l2i], B1[u], a1, 0, 0, 0);
            a2 = __builtin_amdgcn_mfma_f32_16x16x32_f16(sm.w2[5][l2i], B1[u], a2, 0, 0, 0);
            a3 = __builtin_amdgcn_mfma_f32_16x16x32_f16(sm.w2[7][l2i], B1[u], a3, 0, 0, 0);
            C0[u] = act8(a0, a2);
            C1[u] = act8(a1, a3);
        }

        int z3 = 0; asm volatile("" : "+v"(z3));
        const int l3i = lane + z3;
        half8 D0[2], D1[2];
        #pragma unroll
        for (int u = 0; u < 2; ++u) {
            floatx4 a0 = __builtin_amdgcn_mfma_f32_16x16x32_f16(sm.w3[0][l3i], C0[u], sm.b3[0][l3i], 0, 0, 0);
            floatx4 a1 = __builtin_amdgcn_mfma_f32_16x16x32_f16(sm.w3[2][l3i], C0[u], sm.b3[1][l3i], 0, 0, 0);
            floatx4 a2 = __builtin_amdgcn_mfma_f32_16x16x32_f16(sm.w3[4][l3i], C0[u], sm.b3[2][l3i], 0, 0, 0);
            floatx4 a3 = __builtin_amdgcn_mfma_f32_16x16x32_f16(sm.w3[6][l3i], C0[u], sm.b3[3][l3i], 0, 0, 0);
            a0 = __builtin_amdgcn_mfma_f32_16x16x32_f16(sm.w3[1][l3i], C1[u], a0, 0, 0, 0);
            a1 = __builtin_amdgcn_mfma_f32_16x16x32_f16(sm.w3[3][l3i], C1[u], a1, 0, 0, 0);
            a2 = __builtin_amdgcn_mfma_f32_16x16x32_f16(sm.w3[5][l3i], C1[u], a2, 0, 0, 0);
            a3 = __builtin_amdgcn_mfma_f32_16x16x32_f16(sm.w3[7][l3i], C1[u], a3, 0, 0, 0);
            D0[u] = act8(a0, a2);
            D1[u] = act8(a1, a3);
        }

        // ---- layer 4 + store ----
        floatx4 a4[2];
        #pragma unroll
        for (int u = 0; u < 2; ++u) {
            a4[u] = __builtin_amdgcn_mfma_f32_16x16x32_f16(w4f[0], D0[u], a4init, 0, 0, 0);
            a4[u] = __builtin_amdgcn_mfma_f32_16x16x32_f16(w4f[1], D1[u], a4[u], 0, 0, 0);
        }
        if (q == 0) {
            out[(pair << 5) + m]      = act_rev(a4[0][0]);
            out[(pair << 5) + 16 + m] = act_rev(a4[1][0]);
        }

        xv0 = xn0; xv1 = xn1;
        pair = np;
    }
}

extern "C" void kernel_launch(void* const* d_in, const int* in_sizes, int n_in,
                              void* d_out, int out_size, void* d_ws, size_t ws_size,
                              hipStream_t stream) {
    const float* x  = (const float*)d_in[0];
    const float* W1 = (const float*)d_in[1];
    const float* b1 = (const float*)d_in[2];
    const float* W2 = (const float*)d_in[3];
    const float* b2 = (const float*)d_in[4];
    const float* W3 = (const float*)d_in[5];
    const float* b3 = (const float*)d_in[6];
    const float* W4 = (const float*)d_in[7];
    const float* b4 = (const float*)d_in[8];
    float* out = (float*)d_out;
    const int N = out_size;          // 2097152, divisible by 32

    // 2560 blocks x 4 waves = 10240 waves; 65536 tile-pairs -> 6.4 pairs/wave
    // via grid-stride. 5 resident 256-thread blocks/CU (123KB LDS).
    mlp_fused<<<dim3(2560), dim3(256), 0, stream>>>(x, W1, b1, W2, b2, W3, b3, W4, b4, out, N);
}

// Round 16
// 156.570 us; speedup vs baseline: 1.1053x; 1.0776x over previous
//
#include <hip/hip_runtime.h>

typedef _Float16 half8  __attribute__((ext_vector_type(8)));
typedef _Float16 half4v __attribute__((ext_vector_type(4)));
typedef _Float16 half2v __attribute__((ext_vector_type(2)));
typedef float    floatx4 __attribute__((ext_vector_type(4)));
typedef float    float2v __attribute__((ext_vector_type(2)));

static constexpr float INVPI = 0.3183098861837907f;  // weights pre-scaled by 1/pi:
static constexpr float RLOG  = 3.82843f;             // MFMA emits 2*theta in revolutions

// Fused activation via double-angle: x0 = 0.5+0.5cos(theta), two logistic
// iters => h = A + B u + D u^2 with u = cos^2(theta). Using
// u = (1+cos(2theta))/2 and c2 = cos(2theta) (one v_cos, weights at 1/pi):
//   h = E + c2*(F + G*c2);  E=A+B/2+D/4, F=(B+D)/2, G=D/4.  (exact algebra;
// constants match the R14-verified alpha/beta/gamma.) Saves the u=c*c op:
// tail is 2 pk ops instead of 3 -- the kernel is issue-slot bound (R10-R15:
// VALU busy/tile pinned at ~1125 cyc across occupancy 43-85%).
static constexpr double RD = (double)RLOG;
static constexpr double AD = RD*RD/4.0 - RD*RD*RD/16.0;
static constexpr double BD = -RD*RD/4.0 + RD*RD*RD/8.0;
static constexpr double DD = -RD*RD*RD/16.0;
static constexpr float ACT_E = (float)(AD + BD/2.0 + DD/4.0);   //  0.955347
static constexpr float ACT_F = (float)((BD + DD)/2.0);          // -0.078584
static constexpr float ACT_G = (float)(DD/4.0);                 // -0.876763

__device__ __forceinline__ float act_rev(float a2) {   // a2 = 2*theta in revs
    float c = __builtin_amdgcn_cosf(a2);
    float t = __builtin_fmaf(ACT_G, c, ACT_F);
    return __builtin_fmaf(c, t, ACT_E);
}

// Two C-frags (tiles t, t+2) -> next-layer B-frag directly (no cat shuffles).
// Per 2 activations: 2 v_cos + 2 packed-f32 ops + 1 cvt_pkrtz.
__device__ __forceinline__ half8 act8(floatx4 a, floatx4 b) {
    float2v c0 = { __builtin_amdgcn_cosf(a[0]), __builtin_amdgcn_cosf(a[1]) };
    float2v c1 = { __builtin_amdgcn_cosf(a[2]), __builtin_amdgcn_cosf(a[3]) };
    float2v c2 = { __builtin_amdgcn_cosf(b[0]), __builtin_amdgcn_cosf(b[1]) };
    float2v c3 = { __builtin_amdgcn_cosf(b[2]), __builtin_amdgcn_cosf(b[3]) };
    float2v t0 = __builtin_elementwise_fma(c0, (float2v)(ACT_G), (float2v)(ACT_F));
    float2v t1 = __builtin_elementwise_fma(c1, (float2v)(ACT_G), (float2v)(ACT_F));
    float2v t2 = __builtin_elementwise_fma(c2, (float2v)(ACT_G), (float2v)(ACT_F));
    float2v t3 = __builtin_elementwise_fma(c3, (float2v)(ACT_G), (float2v)(ACT_F));
    float2v h0 = __builtin_elementwise_fma(c0, t0, (float2v)(ACT_E));
    float2v h1 = __builtin_elementwise_fma(c1, t1, (float2v)(ACT_E));
    float2v h2 = __builtin_elementwise_fma(c2, t2, (float2v)(ACT_E));
    float2v h3 = __builtin_elementwise_fma(c3, t3, (float2v)(ACT_E));
    half2v e0 = __builtin_bit_cast(half2v, __builtin_amdgcn_cvt_pkrtz(h0.x, h0.y));
    half2v e1 = __builtin_bit_cast(half2v, __builtin_amdgcn_cvt_pkrtz(h1.x, h1.y));
    half2v e2 = __builtin_bit_cast(half2v, __builtin_amdgcn_cvt_pkrtz(h2.x, h2.y));
    half2v e3 = __builtin_bit_cast(half2v, __builtin_amdgcn_cvt_pkrtz(h3.x, h3.y));
    half4v lo = __builtin_shufflevector(e0, e1, 0, 1, 2, 3);
    half4v hi = __builtin_shufflevector(e2, e3, 0, 1, 2, 3);
    return __builtin_shufflevector(lo, hi, 0, 1, 2, 3, 4, 5, 6, 7);
}

// Per-block LDS weight cache (R9/R11-proven; R12 showed biases-in-regs spill
// at the (512,8) 64-reg cap -- biases stay in LDS). R11 config exactly:
// 512-thread block, 4 resident blocks/CU, grid 2048.
struct SMem {
    half8   w2[8][64];   // [(t*2+c)][lane]
    half8   w3[8][64];
    floatx4 b2[4][64];   // [t][lane]
    floatx4 b3[4][64];
};

__global__ __launch_bounds__(512, 8) void mlp_fused(
    const float* __restrict__ x,
    const float* __restrict__ W1, const float* __restrict__ b1,
    const float* __restrict__ W2, const float* __restrict__ b2,
    const float* __restrict__ W3, const float* __restrict__ b3,
    const float* __restrict__ W4, const float* __restrict__ b4,
    float* __restrict__ out, int N)
{
    __shared__ SMem sm;
    const int lane = threadIdx.x & 63;
    const int wib  = threadIdx.x >> 6;   // 0..7
    const int m    = lane & 15;   // sample / C col / A row
    const int q    = lane >> 4;   // quad
    const float s  = INVPI;      // all layers: 1/pi scaling (double-angle form)
    const floatx4 zero4 = {0.0f, 0.0f, 0.0f, 0.0f};

    // ---- in-register persistent frags (small): L1 and L4 ----
    // L1 A-frag (tile t), lanes q==0: [w0h, w0h, w0l, w1h, w1h, w1l, b1h, b1l]
    half8 w1f[4];
    #pragma unroll
    for (int t = 0; t < 4; ++t) {
        half8 v = {};
        if (q == 0) {
            const int n = 16 * t + m;
            float w0 = W1[2*n] * s, w1 = W1[2*n+1] * s, bb = b1[n] * s;
            _Float16 w0h = (_Float16)w0; float w0l = w0 - (float)w0h;
            _Float16 w1h = (_Float16)w1; float w1l = w1 - (float)w1h;
            _Float16 bh  = (_Float16)bb; float bl  = bb - (float)bh;
            v[0] = w0h; v[1] = w0h; v[2] = (_Float16)w0l;
            v[3] = w1h; v[4] = w1h; v[5] = (_Float16)w1l;
            v[6] = bh;  v[7] = (_Float16)bl;
        }
        w1f[t] = v;
    }
    // L4 A-frag: only out-row m==0 real; sigma column permutation
    //   sigma: k-slot (c,q,j) -> neuron (j<4 ? 16c+4q+j : 16(c+2)+4q+j-4)
    half8 w4f[2] = {half8{}, half8{}};
    if (m == 0) {
        #pragma unroll
        for (int c = 0; c < 2; ++c)
            #pragma unroll
            for (int j = 0; j < 8; ++j) {
                int nu = (j < 4) ? (16 * c + 4 * q + j) : (16 * (c + 2) + 4 * q + j - 4);
                w4f[c][j] = (_Float16)(W4[nu] * s);
            }
    }
    floatx4 a4init = zero4;
    if (q == 0) a4init[0] = b4[0] * s;       // C row 0 = (q=0, r=0)

    // ---- wave-split LDS prep (sigma-permuted columns), one barrier ----
    if (wib == 0) {
        #pragma unroll
        for (int t = 0; t < 4; ++t) {
            const float* r2 = W2 + (16 * t + m) * 64;
            #pragma unroll
            for (int c = 0; c < 2; ++c) {
                floatx4 lo2 = *(const floatx4*)(r2 + 16 * c + 4 * q);
                floatx4 hi2 = *(const floatx4*)(r2 + 16 * (c + 2) + 4 * q);
                half8 v2;
                #pragma unroll
                for (int j = 0; j < 4; ++j) {
                    v2[j]     = (_Float16)(lo2[j] * s);
                    v2[4 + j] = (_Float16)(hi2[j] * s);
                }
                sm.w2[t * 2 + c][lane] = v2;
            }
        }
    } else if (wib == 1) {
        #pragma unroll
        for (int t = 0; t < 4; ++t) {
            const float* r3 = W3 + (16 * t + m) * 64;
            #pragma unroll
            for (int c = 0; c < 2; ++c) {
                floatx4 lo3 = *(const floatx4*)(r3 + 16 * c + 4 * q);
                floatx4 hi3 = *(const floatx4*)(r3 + 16 * (c + 2) + 4 * q);
                half8 v3;
                #pragma unroll
                for (int j = 0; j < 4; ++j) {
                    v3[j]     = (_Float16)(lo3[j] * s);
                    v3[4 + j] = (_Float16)(hi3[j] * s);
                }
                sm.w3[t * 2 + c][lane] = v3;
            }
        }
    } else if (wib == 2) {
        #pragma unroll
        for (int t = 0; t < 4; ++t) {
            sm.b2[t][lane] = *(const floatx4*)(b2 + 16 * t + 4 * q) * s;
            sm.b3[t][lane] = *(const floatx4*)(b3 + 16 * t + 4 * q) * s;
        }
    }
    __syncthreads();

    const int ntiles = N >> 4;
    const int nwaves = (gridDim.x * blockDim.x) >> 6;
    const int gwave  = (int)(blockIdx.x * blockDim.x + threadIdx.x) >> 6;
    const float2* __restrict__ x2 = (const float2*)x;

    int tile = gwave;
    float2 xv = x2[(tile << 4) + m];          // 1-ahead x prefetch
    while (tile < ntiles) {
        const int nt = tile + nwaves;
        float2 xnext;
        if (nt < ntiles) xnext = x2[(nt << 4) + m];

        // L1 B-frag (lanes q==0): [xh, xl, xh, yh, yl, yh, 1, 1]
        half8 xa = {};
        if (q == 0) {
            _Float16 xh = (_Float16)xv.x; float xl = xv.x - (float)xh;
            _Float16 yh = (_Float16)xv.y; float yl = xv.y - (float)yh;
            xa[0] = xh; xa[1] = (_Float16)xl; xa[2] = xh;
            xa[3] = yh; xa[4] = (_Float16)yl; xa[5] = yh;
            xa[6] = (_Float16)1.0f; xa[7] = (_Float16)1.0f;
        }

        // ---- layer 1 (in-register frags) ----
        floatx4 a0 = __builtin_amdgcn_mfma_f32_16x16x32_f16(w1f[0], xa, zero4, 0, 0, 0);
        floatx4 a1 = __builtin_amdgcn_mfma_f32_16x16x32_f16(w1f[1], xa, zero4, 0, 0, 0);
        floatx4 a2 = __builtin_amdgcn_mfma_f32_16x16x32_f16(w1f[2], xa, zero4, 0, 0, 0);
        floatx4 a3 = __builtin_amdgcn_mfma_f32_16x16x32_f16(w1f[3], xa, zero4, 0, 0, 0);
        half8 B0 = act8(a0, a2);
        half8 B1 = act8(a1, a3);

        // Opaque zero per layer: defeats LICM (else the LDS reads hoist back
        // into ~128 live regs and spill) AND staggers reads so peak staging
        // is one layer's worth.
        int z2 = 0; asm volatile("" : "+v"(z2));
        const int l2i = lane + z2;
        a0 = __builtin_amdgcn_mfma_f32_16x16x32_f16(sm.w2[0][l2i], B0, sm.b2[0][l2i], 0, 0, 0);
        a1 = __builtin_amdgcn_mfma_f32_16x16x32_f16(sm.w2[2][l2i], B0, sm.b2[1][l2i], 0, 0, 0);
        a2 = __builtin_amdgcn_mfma_f32_16x16x32_f16(sm.w2[4][l2i], B0, sm.b2[2][l2i], 0, 0, 0);
        a3 = __builtin_amdgcn_mfma_f32_16x16x32_f16(sm.w2[6][l2i], B0, sm.b2[3][l2i], 0, 0, 0);
        a0 = __builtin_amdgcn_mfma_f32_16x16x32_f16(sm.w2[1][l2i], B1, a0, 0, 0, 0);
        a1 = __builtin_amdgcn_mfma_f32_16x16x32_f16(sm.w2[3][l2i], B1, a1, 0, 0, 0);
        a2 = __builtin_amdgcn_mfma_f32_16x16x32_f16(sm.w2[5][l2i], B1, a2, 0, 0, 0);
        a3 = __builtin_amdgcn_mfma_f32_16x16x32_f16(sm.w2[7][l2i], B1, a3, 0, 0, 0);
        half8 C0 = act8(a0, a2);
        half8 C1 = act8(a1, a3);

        int z3 = 0; asm volatile("" : "+v"(z3));
        const int l3i = lane + z3;
        a0 = __builtin_amdgcn_mfma_f32_16x16x32_f16(sm.w3[0][l3i], C0, sm.b3[0][l3i], 0, 0, 0);
        a1 = __builtin_amdgcn_mfma_f32_16x16x32_f16(sm.w3[2][l3i], C0, sm.b3[1][l3i], 0, 0, 0);
        a2 = __builtin_amdgcn_mfma_f32_16x16x32_f16(sm.w3[4][l3i], C0, sm.b3[2][l3i], 0, 0, 0);
        a3 = __builtin_amdgcn_mfma_f32_16x16x32_f16(sm.w3[6][l3i], C0, sm.b3[3][l3i], 0, 0, 0);
        a0 = __builtin_amdgcn_mfma_f32_16x16x32_f16(sm.w3[1][l3i], C1, a0, 0, 0, 0);
        a1 = __builtin_amdgcn_mfma_f32_16x16x32_f16(sm.w3[3][l3i], C1, a1, 0, 0, 0);
        a2 = __builtin_amdgcn_mfma_f32_16x16x32_f16(sm.w3[5][l3i], C1, a2, 0, 0, 0);
        a3 = __builtin_amdgcn_mfma_f32_16x16x32_f16(sm.w3[7][l3i], C1, a3, 0, 0, 0);
        half8 D0 = act8(a0, a2);
        half8 D1 = act8(a1, a3);

        // ---- layer 4 + store ----
        floatx4 a4 = __builtin_amdgcn_mfma_f32_16x16x32_f16(w4f[0], D0, a4init, 0, 0, 0);
        a4 = __builtin_amdgcn_mfma_f32_16x16x32_f16(w4f[1], D1, a4, 0, 0, 0);
        if (q == 0)
            out[(tile << 4) + m] = act_rev(a4[0]);

        xv = xnext;
        tile = nt;
    }
}

extern "C" void kernel_launch(void* const* d_in, const int* in_sizes, int n_in,
                              void* d_out, int out_size, void* d_ws, size_t ws_size,
                              hipStream_t stream) {
    const float* x  = (const float*)d_in[0];
    const float* W1 = (const float*)d_in[1];
    const float* b1 = (const float*)d_in[2];
    const float* W2 = (const float*)d_in[3];
    const float* b2 = (const float*)d_in[4];
    const float* W3 = (const float*)d_in[5];
    const float* b3 = (const float*)d_in[6];
    const float* W4 = (const float*)d_in[7];
    const float* b4 = (const float*)d_in[8];
    float* out = (float*)d_out;
    const int N = out_size;          // 2097152, divisible by 16

    // R11-best config: 2048 blocks x 8 waves = 16384 waves; 131072 tiles ->
    // 8 tiles/wave. 4 resident 512-thread blocks/CU at 24.6KB LDS each.
    mlp_fused<<<dim3(2048), dim3(512), 0, stream>>>(x, W1, b1, W2, b2, W3, b3, W4, b4, out, N);
}

// Round 19
// 155.232 us; speedup vs baseline: 1.1148x; 1.0086x over previous
//
#include <hip/hip_runtime.h>

typedef _Float16 half8  __attribute__((ext_vector_type(8)));
typedef _Float16 half4v __attribute__((ext_vector_type(4)));
typedef _Float16 half2v __attribute__((ext_vector_type(2)));
typedef float    floatx4 __attribute__((ext_vector_type(4)));
typedef float    float2v __attribute__((ext_vector_type(2)));

static constexpr float INVPI = 0.3183098861837907f;  // weights pre-scaled by 1/pi:
static constexpr float RLOG  = 3.82843f;             // MFMA emits 2*theta in revolutions

// Fused activation via double-angle (R16-verified): h = E + c2*(F + G*c2),
// c2 = cos(2theta), one v_cos per value, 2 FMAs.
// NOTE: v_pk_fma_f32 inline-asm replacements for the tail FAILED numerically
// twice (R17/R18, absmax 0.31, identical with/without op_sel modifiers) --
// do NOT retry without disassembly-level verification.
static constexpr double RD = (double)RLOG;
static constexpr double AD = RD*RD/4.0 - RD*RD*RD/16.0;
static constexpr double BD = -RD*RD/4.0 + RD*RD*RD/8.0;
static constexpr double DD = -RD*RD*RD/16.0;
static constexpr float ACT_E = (float)(AD + BD/2.0 + DD/4.0);   //  0.955347
static constexpr float ACT_F = (float)((BD + DD)/2.0);          // -0.078584
static constexpr float ACT_G = (float)(DD/4.0);                 // -0.876763

__device__ __forceinline__ float act_rev(float a2) {   // a2 = 2*theta in revs
    float c = __builtin_amdgcn_cosf(a2);
    float t = __builtin_fmaf(ACT_G, c, ACT_F);
    return __builtin_fmaf(c, t, ACT_E);
}

// Two C-frags (tiles t, t+2) -> next-layer B-frag directly (no cat shuffles).
// Per 2 activations: 2 v_cos + 2 fma-pairs + 1 cvt_pkrtz.
__device__ __forceinline__ half8 act8(floatx4 a, floatx4 b) {
    float2v c0 = { __builtin_amdgcn_cosf(a[0]), __builtin_amdgcn_cosf(a[1]) };
    float2v c1 = { __builtin_amdgcn_cosf(a[2]), __builtin_amdgcn_cosf(a[3]) };
    float2v c2 = { __builtin_amdgcn_cosf(b[0]), __builtin_amdgcn_cosf(b[1]) };
    float2v c3 = { __builtin_amdgcn_cosf(b[2]), __builtin_amdgcn_cosf(b[3]) };
    float2v t0 = __builtin_elementwise_fma(c0, (float2v)(ACT_G), (float2v)(ACT_F));
    float2v t1 = __builtin_elementwise_fma(c1, (float2v)(ACT_G), (float2v)(ACT_F));
    float2v t2 = __builtin_elementwise_fma(c2, (float2v)(ACT_G), (float2v)(ACT_F));
    float2v t3 = __builtin_elementwise_fma(c3, (float2v)(ACT_G), (float2v)(ACT_F));
    float2v h0 = __builtin_elementwise_fma(c0, t0, (float2v)(ACT_E));
    float2v h1 = __builtin_elementwise_fma(c1, t1, (float2v)(ACT_E));
    float2v h2 = __builtin_elementwise_fma(c2, t2, (float2v)(ACT_E));
    float2v h3 = __builtin_elementwise_fma(c3, t3, (float2v)(ACT_E));
    half2v e0 = __builtin_bit_cast(half2v, __builtin_amdgcn_cvt_pkrtz(h0.x, h0.y));
    half2v e1 = __builtin_bit_cast(half2v, __builtin_amdgcn_cvt_pkrtz(h1.x, h1.y));
    half2v e2 = __builtin_bit_cast(half2v, __builtin_amdgcn_cvt_pkrtz(h2.x, h2.y));
    half2v e3 = __builtin_bit_cast(half2v, __builtin_amdgcn_cvt_pkrtz(h3.x, h3.y));
    half4v lo = __builtin_shufflevector(e0, e1, 0, 1, 2, 3);
    half4v hi = __builtin_shufflevector(e2, e3, 0, 1, 2, 3);
    return __builtin_shufflevector(lo, hi, 0, 1, 2, 3, 4, 5, 6, 7);
}

// Per-block LDS weight cache (R9/R11-proven; R12 showed biases-in-regs spill
// at the (512,8) 64-reg cap -- biases stay in LDS). R11/R16 config exactly:
// 512-thread block, 4 resident blocks/CU, grid 2048.
struct SMem {
    half8   w2[8][64];   // [(t*2+c)][lane]
    half8   w3[8][64];
    floatx4 b2[4][64];   // [t][lane]
    floatx4 b3[4][64];
};

__global__ __launch_bounds__(512, 8) void mlp_fused(
    const float* __restrict__ x,
    const float* __restrict__ W1, const float* __restrict__ b1,
    const float* __restrict__ W2, const float* __restrict__ b2,
    const float* __restrict__ W3, const float* __restrict__ b3,
    const float* __restrict__ W4, const float* __restrict__ b4,
    float* __restrict__ out, int N)
{
    __shared__ SMem sm;
    const int lane = threadIdx.x & 63;
    const int wib  = threadIdx.x >> 6;   // 0..7
    const int m    = lane & 15;   // sample / C col / A row
    const int q    = lane >> 4;   // quad
    const float s  = INVPI;      // all layers: 1/pi scaling (double-angle form)
    const floatx4 zero4 = {0.0f, 0.0f, 0.0f, 0.0f};

    // ---- in-register persistent frags (small): L1 and L4 ----
    // L1 A-frag (tile t), lanes q==0: [w0h, w0h, w0l, w1h, w1h, w1l, b1h, b1l]
    half8 w1f[4];
    #pragma unroll
    for (int t = 0; t < 4; ++t) {
        half8 v = {};
        if (q == 0) {
            const int n = 16 * t + m;
            float w0 = W1[2*n] * s, w1 = W1[2*n+1] * s, bb = b1[n] * s;
            _Float16 w0h = (_Float16)w0; float w0l = w0 - (float)w0h;
            _Float16 w1h = (_Float16)w1; float w1l = w1 - (float)w1h;
            _Float16 bh  = (_Float16)bb; float bl  = bb - (float)bh;
            v[0] = w0h; v[1] = w0h; v[2] = (_Float16)w0l;
            v[3] = w1h; v[4] = w1h; v[5] = (_Float16)w1l;
            v[6] = bh;  v[7] = (_Float16)bl;
        }
        w1f[t] = v;
    }
    // L4 A-frag: only out-row m==0 real; sigma column permutation
    //   sigma: k-slot (c,q,j) -> neuron (j<4 ? 16c+4q+j : 16(c+2)+4q+j-4)
    half8 w4f[2] = {half8{}, half8{}};
    if (m == 0) {
        #pragma unroll
        for (int c = 0; c < 2; ++c)
            #pragma unroll
            for (int j = 0; j < 8; ++j) {
                int nu = (j < 4) ? (16 * c + 4 * q + j) : (16 * (c + 2) + 4 * q + j - 4);
                w4f[c][j] = (_Float16)(W4[nu] * s);
            }
    }
    floatx4 a4init = zero4;
    if (q == 0) a4init[0] = b4[0] * s;       // C row 0 = (q=0, r=0)

    // ---- wave-split LDS prep (sigma-permuted columns), one barrier ----
    if (wib == 0) {
        #pragma unroll
        for (int t = 0; t < 4; ++t) {
            const float* r2 = W2 + (16 * t + m) * 64;
            #pragma unroll
            for (int c = 0; c < 2; ++c) {
                floatx4 lo2 = *(const floatx4*)(r2 + 16 * c + 4 * q);
                floatx4 hi2 = *(const floatx4*)(r2 + 16 * (c + 2) + 4 * q);
                half8 v2;
                #pragma unroll
                for (int j = 0; j < 4; ++j) {
                    v2[j]     = (_Float16)(lo2[j] * s);
                    v2[4 + j] = (_Float16)(hi2[j] * s);
                }
                sm.w2[t * 2 + c][lane] = v2;
            }
        }
    } else if (wib == 1) {
        #pragma unroll
        for (int t = 0; t < 4; ++t) {
            const float* r3 = W3 + (16 * t + m) * 64;
            #pragma unroll
            for (int c = 0; c < 2; ++c) {
                floatx4 lo3 = *(const floatx4*)(r3 + 16 * c + 4 * q);
                floatx4 hi3 = *(const floatx4*)(r3 + 16 * (c + 2) + 4 * q);
                half8 v3;
                #pragma unroll
                for (int j = 0; j < 4; ++j) {
                    v3[j]     = (_Float16)(lo3[j] * s);
                    v3[4 + j] = (_Float16)(hi3[j] * s);
                }
                sm.w3[t * 2 + c][lane] = v3;
            }
        }
    } else if (wib == 2) {
        #pragma unroll
        for (int t = 0; t < 4; ++t) {
            sm.b2[t][lane] = *(const floatx4*)(b2 + 16 * t + 4 * q) * s;
            sm.b3[t][lane] = *(const floatx4*)(b3 + 16 * t + 4 * q) * s;
        }
    }
    __syncthreads();

    const int ntiles = N >> 4;
    const int nwaves = (gridDim.x * blockDim.x) >> 6;
    const int gwave  = (int)(blockIdx.x * blockDim.x + threadIdx.x) >> 6;
    const float2* __restrict__ x2 = (const float2*)x;

    int tile = gwave;
    float2 xv = x2[(tile << 4) + m];          // 1-ahead x prefetch
    while (tile < ntiles) {
        const int nt = tile + nwaves;
        float2 xnext;
        if (nt < ntiles) xnext = x2[(nt << 4) + m];

        // L1 B-frag (lanes q==0): [xh, xl, xh, yh, yl, yh, 1, 1]
        half8 xa = {};
        if (q == 0) {
            _Float16 xh = (_Float16)xv.x; float xl = xv.x - (float)xh;
            _Float16 yh = (_Float16)xv.y; float yl = xv.y - (float)yh;
            xa[0] = xh; xa[1] = (_Float16)xl; xa[2] = xh;
            xa[3] = yh; xa[4] = (_Float16)yl; xa[5] = yh;
            xa[6] = (_Float16)1.0f; xa[7] = (_Float16)1.0f;
        }

        // ---- layer 1 (in-register frags) ----
        floatx4 a0 = __builtin_amdgcn_mfma_f32_16x16x32_f16(w1f[0], xa, zero4, 0, 0, 0);
        floatx4 a1 = __builtin_amdgcn_mfma_f32_16x16x32_f16(w1f[1], xa, zero4, 0, 0, 0);
        floatx4 a2 = __builtin_amdgcn_mfma_f32_16x16x32_f16(w1f[2], xa, zero4, 0, 0, 0);
        floatx4 a3 = __builtin_amdgcn_mfma_f32_16x16x32_f16(w1f[3], xa, zero4, 0, 0, 0);
        half8 B0 = act8(a0, a2);
        half8 B1 = act8(a1, a3);

        // Opaque zero per layer: defeats LICM (else the LDS reads hoist back
        // into ~128 live regs and spill) AND staggers reads so peak staging
        // is one layer's worth.
        int z2 = 0; asm volatile("" : "+v"(z2));
        const int l2i = lane + z2;
        a0 = __builtin_amdgcn_mfma_f32_16x16x32_f16(sm.w2[0][l2i], B0, sm.b2[0][l2i], 0, 0, 0);
        a1 = __builtin_amdgcn_mfma_f32_16x16x32_f16(sm.w2[2][l2i], B0, sm.b2[1][l2i], 0, 0, 0);
        a2 = __builtin_amdgcn_mfma_f32_16x16x32_f16(sm.w2[4][l2i], B0, sm.b2[2][l2i], 0, 0, 0);
        a3 = __builtin_amdgcn_mfma_f32_16x16x32_f16(sm.w2[6][l2i], B0, sm.b2[3][l2i], 0, 0, 0);
        a0 = __builtin_amdgcn_mfma_f32_16x16x32_f16(sm.w2[1][l2i], B1, a0, 0, 0, 0);
        a1 = __builtin_amdgcn_mfma_f32_16x16x32_f16(sm.w2[3][l2i], B1, a1, 0, 0, 0);
        a2 = __builtin_amdgcn_mfma_f32_16x16x32_f16(sm.w2[5][l2i], B1, a2, 0, 0, 0);
        a3 = __builtin_amdgcn_mfma_f32_16x16x32_f16(sm.w2[7][l2i], B1, a3, 0, 0, 0);
        half8 C0 = act8(a0, a2);
        half8 C1 = act8(a1, a3);

        int z3 = 0; asm volatile("" : "+v"(z3));
        const int l3i = lane + z3;
        a0 = __builtin_amdgcn_mfma_f32_16x16x32_f16(sm.w3[0][l3i], C0, sm.b3[0][l3i], 0, 0, 0);
        a1 = __builtin_amdgcn_mfma_f32_16x16x32_f16(sm.w3[2][l3i], C0, sm.b3[1][l3i], 0, 0, 0);
        a2 = __builtin_amdgcn_mfma_f32_16x16x32_f16(sm.w3[4][l3i], C0, sm.b3[2][l3i], 0, 0, 0);
        a3 = __builtin_amdgcn_mfma_f32_16x16x32_f16(sm.w3[6][l3i], C0, sm.b3[3][l3i], 0, 0, 0);
        a0 = __builtin_amdgcn_mfma_f32_16x16x32_f16(sm.w3[1][l3i], C1, a0, 0, 0, 0);
        a1 = __builtin_amdgcn_mfma_f32_16x16x32_f16(sm.w3[3][l3i], C1, a1, 0, 0, 0);
        a2 = __builtin_amdgcn_mfma_f32_16x16x32_f16(sm.w3[5][l3i], C1, a2, 0, 0, 0);
        a3 = __builtin_amdgcn_mfma_f32_16x16x32_f16(sm.w3[7][l3i], C1, a3, 0, 0, 0);
        half8 D0 = act8(a0, a2);
        half8 D1 = act8(a1, a3);

        // ---- layer 4 + store ----
        floatx4 a4 = __builtin_amdgcn_mfma_f32_16x16x32_f16(w4f[0], D0, a4init, 0, 0, 0);
        a4 = __builtin_amdgcn_mfma_f32_16x16x32_f16(w4f[1], D1, a4, 0, 0, 0);
        if (q == 0)
            out[(tile << 4) + m] = act_rev(a4[0]);

        xv = xnext;
        tile = nt;
    }
}

extern "C" void kernel_launch(void* const* d_in, const int* in_sizes, int n_in,
                              void* d_out, int out_size, void* d_ws, size_t ws_size,
                              hipStream_t stream) {
    const float* x  = (const float*)d_in[0];
    const float* W1 = (const float*)d_in[1];
    const float* b1 = (const float*)d_in[2];
    const float* W2 = (const float*)d_in[3];
    const float* b2 = (const float*)d_in[4];
    const float* W3 = (const float*)d_in[5];
    const float* b3 = (const float*)d_in[6];
    const float* W4 = (const float*)d_in[7];
    const float* b4 = (const float*)d_in[8];
    float* out = (float*)d_out;
    const int N = out_size;          // 2097152, divisible by 16

    // R11/R16-best config: 2048 blocks x 8 waves = 16384 waves; 131072 tiles
    // -> 8 tiles/wave. 4 resident 512-thread blocks/CU at 24.6KB LDS each.
    mlp_fused<<<dim3(2048), dim3(512), 0, stream>>>(x, W1, b1, W2, b2, W3, b3, W4, b4, out, N);
}

// Round 20
// 145.467 us; speedup vs baseline: 1.1896x; 1.0671x over previous
//
#include <hip/hip_runtime.h>

typedef _Float16 half8  __attribute__((ext_vector_type(8)));
typedef _Float16 half4v __attribute__((ext_vector_type(4)));
typedef _Float16 half2v __attribute__((ext_vector_type(2)));
typedef float    floatx4 __attribute__((ext_vector_type(4)));
typedef float    float2v __attribute__((ext_vector_type(2)));

static constexpr float INVPI = 0.3183098861837907f;  // weights pre-scaled by 1/pi:
static constexpr float RLOG  = 3.82843f;             // MFMA emits 2*theta in revolutions

// Fused activation via double-angle (R16-verified): h = E + c2*(F + G*c2),
// c2 = cos(2theta), one v_cos per value.
// Tail now in PACKED F16 (v_pk_fma_f16 -- compiler-native for half2 fma;
// the f32 v_pk_fma_f32 inline-asm path FAILED numerically twice (R17/R18),
// do not retry it).
static constexpr double RD = (double)RLOG;
static constexpr double AD = RD*RD/4.0 - RD*RD*RD/16.0;
static constexpr double BD = -RD*RD/4.0 + RD*RD*RD/8.0;
static constexpr double DD = -RD*RD*RD/16.0;
static constexpr float ACT_E = (float)(AD + BD/2.0 + DD/4.0);   //  0.955347
static constexpr float ACT_F = (float)((BD + DD)/2.0);          // -0.078584
static constexpr float ACT_G = (float)(DD/4.0);                 // -0.876763

__device__ __forceinline__ float act_rev(float a2) {   // a2 = 2*theta in revs (f32: final output)
    float c = __builtin_amdgcn_cosf(a2);
    float t = __builtin_fmaf(ACT_G, c, ACT_F);
    return __builtin_fmaf(c, t, ACT_E);
}

// Two C-frags (tiles t, t+2) -> next-layer B-frag directly.
// Per 8 values: 8 v_cos + 4 cvt_pkrtz + 8 v_pk_fma_f16  (was 8+4+16 w/ f32 tail).
__device__ __forceinline__ half8 act8(floatx4 a, floatx4 b) {
    const half2v Gh = {(_Float16)ACT_G, (_Float16)ACT_G};
    const half2v Fh = {(_Float16)ACT_F, (_Float16)ACT_F};
    const half2v Eh = {(_Float16)ACT_E, (_Float16)ACT_E};
    // cos in f32 (range reduction needs f32 input), then straight to f16 pairs
    half2v c0 = __builtin_bit_cast(half2v, __builtin_amdgcn_cvt_pkrtz(
                    __builtin_amdgcn_cosf(a[0]), __builtin_amdgcn_cosf(a[1])));
    half2v c1 = __builtin_bit_cast(half2v, __builtin_amdgcn_cvt_pkrtz(
                    __builtin_amdgcn_cosf(a[2]), __builtin_amdgcn_cosf(a[3])));
    half2v c2 = __builtin_bit_cast(half2v, __builtin_amdgcn_cvt_pkrtz(
                    __builtin_amdgcn_cosf(b[0]), __builtin_amdgcn_cosf(b[1])));
    half2v c3 = __builtin_bit_cast(half2v, __builtin_amdgcn_cvt_pkrtz(
                    __builtin_amdgcn_cosf(b[2]), __builtin_amdgcn_cosf(b[3])));
    half2v t0 = __builtin_elementwise_fma(c0, Gh, Fh);
    half2v t1 = __builtin_elementwise_fma(c1, Gh, Fh);
    half2v t2 = __builtin_elementwise_fma(c2, Gh, Fh);
    half2v t3 = __builtin_elementwise_fma(c3, Gh, Fh);
    half2v h0 = __builtin_elementwise_fma(c0, t0, Eh);
    half2v h1 = __builtin_elementwise_fma(c1, t1, Eh);
    half2v h2 = __builtin_elementwise_fma(c2, t2, Eh);
    half2v h3 = __builtin_elementwise_fma(c3, t3, Eh);
    half4v lo = __builtin_shufflevector(h0, h1, 0, 1, 2, 3);
    half4v hi = __builtin_shufflevector(h2, h3, 0, 1, 2, 3);
    return __builtin_shufflevector(lo, hi, 0, 1, 2, 3, 4, 5, 6, 7);
}

// Per-block LDS weight cache (R9/R11-proven; R12 showed biases-in-regs spill
// at the (512,8) 64-reg cap -- biases stay in LDS). R11/R16 config exactly:
// 512-thread block, 4 resident blocks/CU, grid 2048.
struct SMem {
    half8   w2[8][64];   // [(t*2+c)][lane]
    half8   w3[8][64];
    floatx4 b2[4][64];   // [t][lane]
    floatx4 b3[4][64];
};

__global__ __launch_bounds__(512, 8) void mlp_fused(
    const float* __restrict__ x,
    const float* __restrict__ W1, const float* __restrict__ b1,
    const float* __restrict__ W2, const float* __restrict__ b2,
    const float* __restrict__ W3, const float* __restrict__ b3,
    const float* __restrict__ W4, const float* __restrict__ b4,
    float* __restrict__ out, int N)
{
    __shared__ SMem sm;
    const int lane = threadIdx.x & 63;
    const int wib  = threadIdx.x >> 6;   // 0..7
    const int m    = lane & 15;   // sample / C col / A row
    const int q    = lane >> 4;   // quad
    const float s  = INVPI;      // all layers: 1/pi scaling (double-angle form)
    const floatx4 zero4 = {0.0f, 0.0f, 0.0f, 0.0f};

    // ---- in-register persistent frags (small): L1 and L4 ----
    // L1 A-frag (tile t), lanes q==0: [w0h, w0h, w0l, w1h, w1h, w1l, b1h, b1l]
    half8 w1f[4];
    #pragma unroll
    for (int t = 0; t < 4; ++t) {
        half8 v = {};
        if (q == 0) {
            const int n = 16 * t + m;
            float w0 = W1[2*n] * s, w1 = W1[2*n+1] * s, bb = b1[n] * s;
            _Float16 w0h = (_Float16)w0; float w0l = w0 - (float)w0h;
            _Float16 w1h = (_Float16)w1; float w1l = w1 - (float)w1h;
            _Float16 bh  = (_Float16)bb; float bl  = bb - (float)bh;
            v[0] = w0h; v[1] = w0h; v[2] = (_Float16)w0l;
            v[3] = w1h; v[4] = w1h; v[5] = (_Float16)w1l;
            v[6] = bh;  v[7] = (_Float16)bl;
        }
        w1f[t] = v;
    }
    // L4 A-frag: only out-row m==0 real; sigma column permutation
    //   sigma: k-slot (c,q,j) -> neuron (j<4 ? 16c+4q+j : 16(c+2)+4q+j-4)
    half8 w4f[2] = {half8{}, half8{}};
    if (m == 0) {
        #pragma unroll
        for (int c = 0; c < 2; ++c)
            #pragma unroll
            for (int j = 0; j < 8; ++j) {
                int nu = (j < 4) ? (16 * c + 4 * q + j) : (16 * (c + 2) + 4 * q + j - 4);
                w4f[c][j] = (_Float16)(W4[nu] * s);
            }
    }
    floatx4 a4init = zero4;
    if (q == 0) a4init[0] = b4[0] * s;       // C row 0 = (q=0, r=0)

    // ---- wave-split LDS prep (sigma-permuted columns), one barrier ----
    if (wib == 0) {
        #pragma unroll
        for (int t = 0; t < 4; ++t) {
            const float* r2 = W2 + (16 * t + m) * 64;
            #pragma unroll
            for (int c = 0; c < 2; ++c) {
                floatx4 lo2 = *(const floatx4*)(r2 + 16 * c + 4 * q);
                floatx4 hi2 = *(const floatx4*)(r2 + 16 * (c + 2) + 4 * q);
                half8 v2;
                #pragma unroll
                for (int j = 0; j < 4; ++j) {
                    v2[j]     = (_Float16)(lo2[j] * s);
                    v2[4 + j] = (_Float16)(hi2[j] * s);
                }
                sm.w2[t * 2 + c][lane] = v2;
            }
        }
    } else if (wib == 1) {
        #pragma unroll
        for (int t = 0; t < 4; ++t) {
            const float* r3 = W3 + (16 * t + m) * 64;
            #pragma unroll
            for (int c = 0; c < 2; ++c) {
                floatx4 lo3 = *(const floatx4*)(r3 + 16 * c + 4 * q);
                floatx4 hi3 = *(const floatx4*)(r3 + 16 * (c + 2) + 4 * q);
                half8 v3;
                #pragma unroll
                for (int j = 0; j < 4; ++j) {
                    v3[j]     = (_Float16)(lo3[j] * s);
                    v3[4 + j] = (_Float16)(hi3[j] * s);
                }
                sm.w3[t * 2 + c][lane] = v3;
            }
        }
    } else if (wib == 2) {
        #pragma unroll
        for (int t = 0; t < 4; ++t) {
            sm.b2[t][lane] = *(const floatx4*)(b2 + 16 * t + 4 * q) * s;
            sm.b3[t][lane] = *(const floatx4*)(b3 + 16 * t + 4 * q) * s;
        }
    }
    __syncthreads();

    const int ntiles = N >> 4;
    const int nwaves = (gridDim.x * blockDim.x) >> 6;
    const int gwave  = (int)(blockIdx.x * blockDim.x + threadIdx.x) >> 6;
    const float2* __restrict__ x2 = (const float2*)x;

    int tile = gwave;
    float2 xv = x2[(tile << 4) + m];          // 1-ahead x prefetch
    while (tile < ntiles) {
        const int nt = tile + nwaves;
        float2 xnext;
        if (nt < ntiles) xnext = x2[(nt << 4) + m];

        // L1 B-frag (lanes q==0): [xh, xl, xh, yh, yl, yh, 1, 1]
        half8 xa = {};
        if (q == 0) {
            _Float16 xh = (_Float16)xv.x; float xl = xv.x - (float)xh;
            _Float16 yh = (_Float16)xv.y; float yl = xv.y - (float)yh;
            xa[0] = xh; xa[1] = (_Float16)xl; xa[2] = xh;
            xa[3] = yh; xa[4] = (_Float16)yl; xa[5] = yh;
            xa[6] = (_Float16)1.0f; xa[7] = (_Float16)1.0f;
        }

        // ---- layer 1 (in-register frags) ----
        floatx4 a0 = __builtin_amdgcn_mfma_f32_16x16x32_f16(w1f[0], xa, zero4, 0, 0, 0);
        floatx4 a1 = __builtin_amdgcn_mfma_f32_16x16x32_f16(w1f[1], xa, zero4, 0, 0, 0);
        floatx4 a2 = __builtin_amdgcn_mfma_f32_16x16x32_f16(w1f[2], xa, zero4, 0, 0, 0);
        floatx4 a3 = __builtin_amdgcn_mfma_f32_16x16x32_f16(w1f[3], xa, zero4, 0, 0, 0);
        half8 B0 = act8(a0, a2);
        half8 B1 = act8(a1, a3);

        // Opaque zero per layer: defeats LICM (else the LDS reads hoist back
        // into ~128 live regs and spill) AND staggers reads so peak staging
        // is one layer's worth.
        int z2 = 0; asm volatile("" : "+v"(z2));
        const int l2i = lane + z2;
        a0 = __builtin_amdgcn_mfma_f32_16x16x32_f16(sm.w2[0][l2i], B0, sm.b2[0][l2i], 0, 0, 0);
        a1 = __builtin_amdgcn_mfma_f32_16x16x32_f16(sm.w2[2][l2i], B0, sm.b2[1][l2i], 0, 0, 0);
        a2 = __builtin_amdgcn_mfma_f32_16x16x32_f16(sm.w2[4][l2i], B0, sm.b2[2][l2i], 0, 0, 0);
        a3 = __builtin_amdgcn_mfma_f32_16x16x32_f16(sm.w2[6][l2i], B0, sm.b2[3][l2i], 0, 0, 0);
        a0 = __builtin_amdgcn_mfma_f32_16x16x32_f16(sm.w2[1][l2i], B1, a0, 0, 0, 0);
        a1 = __builtin_amdgcn_mfma_f32_16x16x32_f16(sm.w2[3][l2i], B1, a1, 0, 0, 0);
        a2 = __builtin_amdgcn_mfma_f32_16x16x32_f16(sm.w2[5][l2i], B1, a2, 0, 0, 0);
        a3 = __builtin_amdgcn_mfma_f32_16x16x32_f16(sm.w2[7][l2i], B1, a3, 0, 0, 0);
        half8 C0 = act8(a0, a2);
        half8 C1 = act8(a1, a3);

        int z3 = 0; asm volatile("" : "+v"(z3));
        const int l3i = lane + z3;
        a0 = __builtin_amdgcn_mfma_f32_16x16x32_f16(sm.w3[0][l3i], C0, sm.b3[0][l3i], 0, 0, 0);
        a1 = __builtin_amdgcn_mfma_f32_16x16x32_f16(sm.w3[2][l3i], C0, sm.b3[1][l3i], 0, 0, 0);
        a2 = __builtin_amdgcn_mfma_f32_16x16x32_f16(sm.w3[4][l3i], C0, sm.b3[2][l3i], 0, 0, 0);
        a3 = __builtin_amdgcn_mfma_f32_16x16x32_f16(sm.w3[6][l3i], C0, sm.b3[3][l3i], 0, 0, 0);
        a0 = __builtin_amdgcn_mfma_f32_16x16x32_f16(sm.w3[1][l3i], C1, a0, 0, 0, 0);
        a1 = __builtin_amdgcn_mfma_f32_16x16x32_f16(sm.w3[3][l3i], C1, a1, 0, 0, 0);
        a2 = __builtin_amdgcn_mfma_f32_16x16x32_f16(sm.w3[5][l3i], C1, a2, 0, 0, 0);
        a3 = __builtin_amdgcn_mfma_f32_16x16x32_f16(sm.w3[7][l3i], C1, a3, 0, 0, 0);
        half8 D0 = act8(a0, a2);
        half8 D1 = act8(a1, a3);

        // ---- layer 4 + store ----
        floatx4 a4 = __builtin_amdgcn_mfma_f32_16x16x32_f16(w4f[0], D0, a4init, 0, 0, 0);
        a4 = __builtin_amdgcn_mfma_f32_16x16x32_f16(w4f[1], D1, a4, 0, 0, 0);
        if (q == 0)
            out[(tile << 4) + m] = act_rev(a4[0]);

        xv = xnext;
        tile = nt;
    }
}

extern "C" void kernel_launch(void* const* d_in, const int* in_sizes, int n_in,
                              void* d_out, int out_size, void* d_ws, size_t ws_size,
                              hipStream_t stream) {
    const float* x  = (const float*)d_in[0];
    const float* W1 = (const float*)d_in[1];
    const float* b1 = (const float*)d_in[2];
    const float* W2 = (const float*)d_in[3];
    const float* b2 = (const float*)d_in[4];
    const float* W3 = (const float*)d_in[5];
    const float* b3 = (const float*)d_in[6];
    const float* W4 = (const float*)d_in[7];
    const float* b4 = (const float*)d_in[8];
    float* out = (float*)d_out;
    const int N = out_size;          // 2097152, divisible by 16

    // R11/R16-best config: 2048 blocks x 8 waves = 16384 waves; 131072 tiles
    // -> 8 tiles/wave. 4 resident 512-thread blocks/CU at 24.6KB LDS each.
    mlp_fused<<<dim3(2048), dim3(512), 0, stream>>>(x, W1, b1, W2, b2, W3, b3, W4, b4, out, N);
}